// Round 2
// baseline (454.318 us; speedup 1.0000x reference)
//
#include <hip/hip_runtime.h>
#include <hip/hip_bf16.h>

// Problem constants (match reference)
#define BB 2048
#define NN 256
#define EE 32
#define HH 64
#define TB 16   // b-tile per block
#define TI 16   // i-tile per block

// ---------------------------------------------------------------------------
// Precompute c[i][h] = b1[h] + sum_e emb[i,e]*W1[N+e,h] + sum_e pemb[i,e]*W1[N+E+e,h]
// where pemb[i,e] = (sum_j A[j,i]*emb[j,e]) / (colsum_i + 1e-8)
// Grid: N blocks of H threads. Trivial cost (<5us).
// ---------------------------------------------------------------------------
__global__ void precompute_c(const float* __restrict__ A,
                             const float* __restrict__ emb,
                             const float* __restrict__ W1,
                             const float* __restrict__ b1,
                             float* __restrict__ c) {
    const int i = blockIdx.x;
    const int t = threadIdx.x;   // 0..63
    __shared__ float pembS[EE];

    // column sum of A (same address across threads -> broadcast, L2-hot)
    float cs = 0.f;
    #pragma unroll 4
    for (int j = 0; j < NN; ++j) cs += A[j * NN + i];
    const float inv = 1.f / (cs + 1e-8f);

    if (t < EE) {
        float pe = 0.f;
        #pragma unroll 4
        for (int j = 0; j < NN; ++j) pe += A[j * NN + i] * emb[j * EE + t];
        pembS[t] = pe * inv;
    }
    __syncthreads();

    float ch = b1[t];
    const float* embi = emb + i * EE;
    #pragma unroll 8
    for (int e = 0; e < EE; ++e) {
        ch = fmaf(embi[e],  W1[(NN      + e) * HH + t], ch);
        ch = fmaf(pembS[e], W1[(NN + EE + e) * HH + t], ch);
    }
    c[i * HH + t] = ch;
}

// ---------------------------------------------------------------------------
// Fused main kernel: one thread owns one (b,i) row.
//   h1_pre[h] = sum_j x[b,j]*A[j,i]*W1[j,h] + c[i,h]
//   -> LN -> leaky -> @W2+b2 -> LN -> leaky -> @W3+b3 -> (mean, log_std)
// x, A tiles staged in LDS (conflict-free broadcast reads); W1/W2/W3/g/b read
// via wave-uniform global addresses so the compiler can scalarize them
// (s_load + v_fmac vD, sW, vS) -- check disasm for this next round.
// ---------------------------------------------------------------------------
__global__ __launch_bounds__(256, 2) void fused_main(
    const float* __restrict__ x, const float* __restrict__ A,
    const float* __restrict__ W1, const float* __restrict__ c,
    const float* __restrict__ g1, const float* __restrict__ bt1,
    const float* __restrict__ W2, const float* __restrict__ b2,
    const float* __restrict__ g2, const float* __restrict__ bt2,
    const float* __restrict__ W3, const float* __restrict__ b3,
    float* __restrict__ out) {

    __shared__ float xs[TB][NN + 1];   // +1 pad: xrow reads hit 4 distinct banks
    __shared__ float As[NN * TI];      // As[j*16+ii]: 16 banks + broadcast, conflict-free

    const int t  = threadIdx.x;
    const int b0 = (blockIdx.x >> 4) * TB;   // 128 b-tiles
    const int i0 = (blockIdx.x & 15) * TI;   // 16  i-tiles

    // Stage x tile (coalesced: consecutive t -> consecutive j)
    for (int idx = t; idx < TB * NN; idx += 256) {
        const int bb = idx >> 8, j = idx & 255;
        xs[bb][j] = x[(b0 + bb) * NN + j];
    }
    // Stage A tile (A is [j][i] row-major; grab columns i0..i0+15)
    for (int idx = t; idx < NN * TI; idx += 256) {
        const int j = idx >> 4, ii = idx & 15;
        As[j * TI + ii] = A[j * NN + i0 + ii];
    }
    __syncthreads();

    const int bi = t >> 4, ii = t & 15;

    float acc[HH];
    #pragma unroll
    for (int h = 0; h < HH; ++h) acc[h] = 0.f;

    const float* xrow = &xs[bi][0];
    const float* acol = &As[ii];

    // Main contraction: 256 j-steps x 64 FMA. W1 row address is wave-uniform.
    #pragma unroll 2
    for (int j = 0; j < NN; ++j) {
        const float s = xrow[j] * acol[j * TI];
        const float* w = W1 + j * HH;
        #pragma unroll
        for (int h = 0; h < HH; ++h) acc[h] = fmaf(s, w[h], acc[h]);
    }

    // + c (per-thread row, L2-hot)
    {
        const float* crow = c + (i0 + ii) * HH;
        #pragma unroll
        for (int h = 0; h < HH; ++h) acc[h] += crow[h];
    }

    // LayerNorm 1 (biased var, eps=1e-5) + leaky relu; g1/bt1 wave-uniform
    {
        float m0 = 0.f, m1 = 0.f, m2 = 0.f, m3 = 0.f;
        #pragma unroll
        for (int h = 0; h < HH; h += 4) { m0 += acc[h]; m1 += acc[h+1]; m2 += acc[h+2]; m3 += acc[h+3]; }
        const float m = (m0 + m1 + m2 + m3) * (1.f / HH);
        float v0 = 0.f, v1 = 0.f, v2 = 0.f, v3 = 0.f;
        #pragma unroll
        for (int h = 0; h < HH; h += 4) {
            float d0 = acc[h] - m, d1 = acc[h+1] - m, d2 = acc[h+2] - m, d3 = acc[h+3] - m;
            v0 = fmaf(d0, d0, v0); v1 = fmaf(d1, d1, v1); v2 = fmaf(d2, d2, v2); v3 = fmaf(d3, d3, v3);
        }
        const float var = (v0 + v1 + v2 + v3) * (1.f / HH);
        const float inv = rsqrtf(var + 1e-5f);
        #pragma unroll
        for (int h = 0; h < HH; ++h) {
            float u = (acc[h] - m) * inv * g1[h] + bt1[h];
            acc[h] = (u >= 0.f) ? u : 0.2f * u;
        }
    }

    // Layer 2: acc2 = acc @ W2 + b2 (W2 rows wave-uniform)
    float acc2[HH];
    #pragma unroll
    for (int ho = 0; ho < HH; ++ho) acc2[ho] = b2[ho];
    for (int h = 0; h < HH; ++h) {
        const float v = acc[h];
        const float* w = W2 + h * HH;
        #pragma unroll
        for (int ho = 0; ho < HH; ++ho) acc2[ho] = fmaf(v, w[ho], acc2[ho]);
    }

    // LayerNorm 2 + leaky
    {
        float m0 = 0.f, m1 = 0.f, m2 = 0.f, m3 = 0.f;
        #pragma unroll
        for (int h = 0; h < HH; h += 4) { m0 += acc2[h]; m1 += acc2[h+1]; m2 += acc2[h+2]; m3 += acc2[h+3]; }
        const float m = (m0 + m1 + m2 + m3) * (1.f / HH);
        float v0 = 0.f, v1 = 0.f, v2 = 0.f, v3 = 0.f;
        #pragma unroll
        for (int h = 0; h < HH; h += 4) {
            float d0 = acc2[h] - m, d1 = acc2[h+1] - m, d2 = acc2[h+2] - m, d3 = acc2[h+3] - m;
            v0 = fmaf(d0, d0, v0); v1 = fmaf(d1, d1, v1); v2 = fmaf(d2, d2, v2); v3 = fmaf(d3, d3, v3);
        }
        const float var = (v0 + v1 + v2 + v3) * (1.f / HH);
        const float inv = rsqrtf(var + 1e-5f);
        #pragma unroll
        for (int h = 0; h < HH; ++h) {
            float u = (acc2[h] - m) * inv * g2[h] + bt2[h];
            acc2[h] = (u >= 0.f) ? u : 0.2f * u;
        }
    }

    // Layer 3: 2 outputs
    float o0 = b3[0], o1 = b3[1];
    #pragma unroll
    for (int h = 0; h < HH; ++h) {
        o0 = fmaf(acc2[h], W3[h * 2 + 0], o0);
        o1 = fmaf(acc2[h], W3[h * 2 + 1], o1);
    }

    const int row = (b0 + bi) * NN + (i0 + ii);
    out[row] = o0;                 // means
    out[BB * NN + row] = o1;       // log_stds
}

extern "C" void kernel_launch(void* const* d_in, const int* in_sizes, int n_in,
                              void* d_out, int out_size, void* d_ws, size_t ws_size,
                              hipStream_t stream) {
    const float* x   = (const float*)d_in[0];
    const float* A   = (const float*)d_in[1];
    const float* emb = (const float*)d_in[2];
    const float* W1  = (const float*)d_in[3];
    const float* b1  = (const float*)d_in[4];
    const float* g1  = (const float*)d_in[5];
    const float* bt1 = (const float*)d_in[6];
    const float* W2  = (const float*)d_in[7];
    const float* b2  = (const float*)d_in[8];
    const float* g2  = (const float*)d_in[9];
    const float* bt2 = (const float*)d_in[10];
    const float* W3  = (const float*)d_in[11];
    const float* b3  = (const float*)d_in[12];
    float* out = (float*)d_out;

    float* c = (float*)d_ws;   // N*H floats = 64 KB scratch

    precompute_c<<<NN, HH, 0, stream>>>(A, emb, W1, b1, c);
    fused_main<<<(BB / TB) * (NN / TI), 256, 0, stream>>>(
        x, A, W1, c, g1, bt1, W2, b2, g2, bt2, W3, b3, out);
}

// Round 7
// 274.571 us; speedup vs baseline: 1.6546x; 1.6546x over previous
//
#include <hip/hip_runtime.h>
#include <hip/hip_bf16.h>

// Problem constants (match reference)
#define BB 2048
#define NN 256
#define EE 32
#define HH 64
#define TB 16   // b-tile per block
#define TI 16   // i-tile per block

typedef __attribute__((ext_vector_type(8))) short s16x8;   // 8 bf16 (4 VGPRs) MFMA A/B frag
typedef __attribute__((ext_vector_type(4))) float f32x4;   // 4 fp32 MFMA C/D frag

__device__ __forceinline__ unsigned short f32_to_bf16_rne(float f) {
    unsigned int u = __float_as_uint(f);
    unsigned int r = u + 0x7FFFu + ((u >> 16) & 1u);
    return (unsigned short)(r >> 16);
}
__device__ __forceinline__ float bf16_to_f32(unsigned short h) {
    return __uint_as_float(((unsigned int)h) << 16);
}

// ---------------------------------------------------------------------------
// Precompute c[i][h] = b1[h] + self-emb + parent-emb contributions (validated).
// ---------------------------------------------------------------------------
__global__ void precompute_c(const float* __restrict__ A,
                             const float* __restrict__ emb,
                             const float* __restrict__ W1,
                             const float* __restrict__ b1,
                             float* __restrict__ c) {
    const int i = blockIdx.x;
    const int t = threadIdx.x;   // 0..63
    __shared__ float pembS[EE];

    float cs = 0.f;
    #pragma unroll 4
    for (int j = 0; j < NN; ++j) cs += A[j * NN + i];
    const float inv = 1.f / (cs + 1e-8f);

    if (t < EE) {
        float pe = 0.f;
        #pragma unroll 4
        for (int j = 0; j < NN; ++j) pe += A[j * NN + i] * emb[j * EE + t];
        pembS[t] = pe * inv;
    }
    __syncthreads();

    float ch = b1[t];
    const float* embi = emb + i * EE;
    #pragma unroll 8
    for (int e = 0; e < EE; ++e) {
        ch = fmaf(embi[e],  W1[(NN      + e) * HH + t], ch);
        ch = fmaf(pembS[e], W1[(NN + EE + e) * HH + t], ch);
    }
    c[i * HH + t] = ch;
}

// ---------------------------------------------------------------------------
// Split W1 (first NN rows only; j<256) into transposed hi/lo bf16:
// w1t_hi/lo[n][k] = bf16 split of W1[k][n].  64 blocks x 256 threads.
// ---------------------------------------------------------------------------
__global__ void prep_w1t(const float* __restrict__ W1,
                         unsigned short* __restrict__ w1t_hi,
                         unsigned short* __restrict__ w1t_lo) {
    const int idx = blockIdx.x * 256 + threadIdx.x;   // 0..16383
    const int n = idx >> 8, k = idx & 255;
    const float w = W1[k * HH + n];
    const unsigned short hb = f32_to_bf16_rne(w);
    const unsigned short lb = f32_to_bf16_rne(w - bf16_to_f32(hb));
    w1t_hi[n * NN + k] = hb;
    w1t_lo[n * NN + k] = lb;
}

// ---------------------------------------------------------------------------
// Fused main kernel.
// Phase 1 (MFMA): h1[r][h] = sum_j s[r][j]*W1[j][h], s built on the fly as
//   xs[b][j]*A[j][i], split hi/lo bf16, 3-MFMA (hihi+hilo+lohi) ~ fp32.
//   A-frag: lane l = row l&15, k = 8*(l>>4)+t (contiguous, per m92 lineage).
//   C-frag: col = lane&15, row = (lane>>4)*4 + reg (verified m89/m91).
// Phase 2 (validated VALU epilogue): +c, LN1, leaky, @W2, LN2, leaky, @W3.
// LDS: 64 KB union — {xs[16][257], AsT[16][260]} overlaid with swizzled
//   h1[256][64] (phases separated by barriers).
// ---------------------------------------------------------------------------
__global__ __launch_bounds__(256, 2) void fused_main(
    const float* __restrict__ x, const float* __restrict__ A,
    const float* __restrict__ c,
    const unsigned short* __restrict__ w1hi,
    const unsigned short* __restrict__ w1lo,
    const float* __restrict__ g1, const float* __restrict__ bt1,
    const float* __restrict__ W2, const float* __restrict__ b2,
    const float* __restrict__ g2, const float* __restrict__ bt2,
    const float* __restrict__ W3, const float* __restrict__ b3,
    float* __restrict__ out) {

    __shared__ float smem[16384];            // 64 KB exactly
    float* xs  = smem;                       // [TB][257]
    float* AsT = smem + TB * 257;            // [TI][260]
    float* h1  = smem;                       // [256][64], XOR-swizzled float4s

    const int t  = threadIdx.x;
    const int b0 = (blockIdx.x >> 4) * TB;
    const int i0 = (blockIdx.x & 15) * TI;

    // ---- stage x tile and transposed A columns ----
    for (int idx = t; idx < TB * NN; idx += 256) {
        const int bb = idx >> 8, j = idx & 255;
        xs[bb * 257 + j] = x[(b0 + bb) * NN + j];
    }
    for (int idx = t; idx < NN * TI; idx += 256) {
        const int j = idx >> 4, ii = idx & 15;
        AsT[ii * 260 + j] = A[j * NN + i0 + ii];
    }
    __syncthreads();

    // ---- Phase 1: MFMA contraction ----
    const int wv = t >> 6;        // wave 0..3 (owns b-rows bi = wv*4 .. wv*4+3)
    const int l  = t & 63;
    const int lg = l >> 4;        // k-group 0..3
    const int lm = l & 15;        // m within tile (= ii), and n within n-tile

    f32x4 acc[4][4];              // [row-tile][n-tile]
    #pragma unroll
    for (int rt = 0; rt < 4; ++rt)
        #pragma unroll
        for (int nt = 0; nt < 4; ++nt) {
            acc[rt][nt][0] = 0.f; acc[rt][nt][1] = 0.f;
            acc[rt][nt][2] = 0.f; acc[rt][nt][3] = 0.f;
        }

    for (int kb = 0; kb < 8; ++kb) {
        const int j0 = kb * 32 + lg * 8;

        // B-frags for all 4 n-tiles (hi & lo), L1/L2-hot global loads
        s16x8 bh[4], bl[4];
        #pragma unroll
        for (int nt = 0; nt < 4; ++nt) {
            const int n = nt * 16 + lm;
            bh[nt] = *(const s16x8*)(w1hi + n * NN + j0);
            bl[nt] = *(const s16x8*)(w1lo + n * NN + j0);
        }

        #pragma unroll
        for (int rt = 0; rt < 4; ++rt) {
            const int bi = wv * 4 + rt;
            const float* xp = &xs[bi * 257 + j0];
            const float* ap = &AsT[lm * 260 + j0];
            const f32x4 x0 = *(const f32x4*)xp;
            const f32x4 x1 = *(const f32x4*)(xp + 4);
            const f32x4 a0 = *(const f32x4*)ap;
            const f32x4 a1 = *(const f32x4*)(ap + 4);

            s16x8 ah, al;
            #pragma unroll
            for (int q = 0; q < 4; ++q) {
                const float p  = x0[q] * a0[q];
                const unsigned short hb = f32_to_bf16_rne(p);
                ah[q] = (short)hb;
                al[q] = (short)f32_to_bf16_rne(p - bf16_to_f32(hb));
            }
            #pragma unroll
            for (int q = 0; q < 4; ++q) {
                const float p  = x1[q] * a1[q];
                const unsigned short hb = f32_to_bf16_rne(p);
                ah[4 + q] = (short)hb;
                al[4 + q] = (short)f32_to_bf16_rne(p - bf16_to_f32(hb));
            }

            #pragma unroll
            for (int nt = 0; nt < 4; ++nt) {
                acc[rt][nt] = __builtin_amdgcn_mfma_f32_16x16x32_bf16(ah, bh[nt], acc[rt][nt], 0, 0, 0);
                acc[rt][nt] = __builtin_amdgcn_mfma_f32_16x16x32_bf16(ah, bl[nt], acc[rt][nt], 0, 0, 0);
                acc[rt][nt] = __builtin_amdgcn_mfma_f32_16x16x32_bf16(al, bh[nt], acc[rt][nt], 0, 0, 0);
            }
        }
    }
    __syncthreads();   // all waves done reading xs/AsT

    // ---- C-frags -> swizzled h1 in LDS ----
    #pragma unroll
    for (int rt = 0; rt < 4; ++rt) {
        const int bi = wv * 4 + rt;
        #pragma unroll
        for (int nt = 0; nt < 4; ++nt) {
            #pragma unroll
            for (int rr = 0; rr < 4; ++rr) {
                const int wr  = bi * 16 + lg * 4 + rr;     // block row (= ii order)
                const int col = nt * 16 + lm;
                const int q   = col >> 2;
                h1[wr * 64 + (((q ^ (wr & 15)) << 2) | (col & 3))] = acc[rt][nt][rr];
            }
        }
    }
    __syncthreads();

    // ---- Phase 2: validated per-row epilogue (thread t owns block-row t) ----
    const int bi = t >> 4, ii = t & 15;

    float acc1[HH];
    #pragma unroll
    for (int q = 0; q < 16; ++q) {
        const f32x4 v = *(const f32x4*)&h1[t * 64 + ((q ^ (t & 15)) << 2)];
        acc1[4*q+0] = v[0]; acc1[4*q+1] = v[1]; acc1[4*q+2] = v[2]; acc1[4*q+3] = v[3];
    }

    // + c
    {
        const float* crow = c + (i0 + ii) * HH;
        #pragma unroll
        for (int h = 0; h < HH; ++h) acc1[h] += crow[h];
    }

    // LayerNorm 1 + leaky relu
    {
        float m0 = 0.f, m1 = 0.f, m2 = 0.f, m3 = 0.f;
        #pragma unroll
        for (int h = 0; h < HH; h += 4) { m0 += acc1[h]; m1 += acc1[h+1]; m2 += acc1[h+2]; m3 += acc1[h+3]; }
        const float m = (m0 + m1 + m2 + m3) * (1.f / HH);
        float v0 = 0.f, v1 = 0.f, v2 = 0.f, v3 = 0.f;
        #pragma unroll
        for (int h = 0; h < HH; h += 4) {
            float d0 = acc1[h] - m, d1 = acc1[h+1] - m, d2 = acc1[h+2] - m, d3 = acc1[h+3] - m;
            v0 = fmaf(d0, d0, v0); v1 = fmaf(d1, d1, v1); v2 = fmaf(d2, d2, v2); v3 = fmaf(d3, d3, v3);
        }
        const float var = (v0 + v1 + v2 + v3) * (1.f / HH);
        const float inv = rsqrtf(var + 1e-5f);
        #pragma unroll
        for (int h = 0; h < HH; ++h) {
            float u = (acc1[h] - m) * inv * g1[h] + bt1[h];
            acc1[h] = (u >= 0.f) ? u : 0.2f * u;
        }
    }

    // Layer 2 (fully unrolled — all indices compile-time constant)
    float acc2[HH];
    #pragma unroll
    for (int ho = 0; ho < HH; ++ho) acc2[ho] = b2[ho];
    #pragma unroll
    for (int h = 0; h < HH; ++h) {
        const float v = acc1[h];
        const float* w = W2 + h * HH;
        #pragma unroll
        for (int ho = 0; ho < HH; ++ho) acc2[ho] = fmaf(v, w[ho], acc2[ho]);
    }

    // LayerNorm 2 + leaky
    {
        float m0 = 0.f, m1 = 0.f, m2 = 0.f, m3 = 0.f;
        #pragma unroll
        for (int h = 0; h < HH; h += 4) { m0 += acc2[h]; m1 += acc2[h+1]; m2 += acc2[h+2]; m3 += acc2[h+3]; }
        const float m = (m0 + m1 + m2 + m3) * (1.f / HH);
        float v0 = 0.f, v1 = 0.f, v2 = 0.f, v3 = 0.f;
        #pragma unroll
        for (int h = 0; h < HH; h += 4) {
            float d0 = acc2[h] - m, d1 = acc2[h+1] - m, d2 = acc2[h+2] - m, d3 = acc2[h+3] - m;
            v0 = fmaf(d0, d0, v0); v1 = fmaf(d1, d1, v1); v2 = fmaf(d2, d2, v2); v3 = fmaf(d3, d3, v3);
        }
        const float var = (v0 + v1 + v2 + v3) * (1.f / HH);
        const float inv = rsqrtf(var + 1e-5f);
        #pragma unroll
        for (int h = 0; h < HH; ++h) {
            float u = (acc2[h] - m) * inv * g2[h] + bt2[h];
            acc2[h] = (u >= 0.f) ? u : 0.2f * u;
        }
    }

    // Layer 3
    float o0 = b3[0], o1 = b3[1];
    #pragma unroll
    for (int h = 0; h < HH; ++h) {
        o0 = fmaf(acc2[h], W3[h * 2 + 0], o0);
        o1 = fmaf(acc2[h], W3[h * 2 + 1], o1);
    }

    const int row = (b0 + bi) * NN + (i0 + ii);
    out[row] = o0;
    out[BB * NN + row] = o1;
}

extern "C" void kernel_launch(void* const* d_in, const int* in_sizes, int n_in,
                              void* d_out, int out_size, void* d_ws, size_t ws_size,
                              hipStream_t stream) {
    const float* x   = (const float*)d_in[0];
    const float* A   = (const float*)d_in[1];
    const float* emb = (const float*)d_in[2];
    const float* W1  = (const float*)d_in[3];
    const float* b1  = (const float*)d_in[4];
    const float* g1  = (const float*)d_in[5];
    const float* bt1 = (const float*)d_in[6];
    const float* W2  = (const float*)d_in[7];
    const float* b2  = (const float*)d_in[8];
    const float* g2  = (const float*)d_in[9];
    const float* bt2 = (const float*)d_in[10];
    const float* W3  = (const float*)d_in[11];
    const float* b3  = (const float*)d_in[12];
    float* out = (float*)d_out;

    // workspace carve: c (64 KB) | w1t_hi (32 KB) | w1t_lo (32 KB)
    float* c = (float*)d_ws;
    unsigned short* w1hi = (unsigned short*)(c + NN * HH);
    unsigned short* w1lo = w1hi + NN * HH;

    precompute_c<<<NN, HH, 0, stream>>>(A, emb, W1, b1, c);
    prep_w1t<<<64, 256, 0, stream>>>(W1, w1hi, w1lo);
    fused_main<<<(BB / TB) * (NN / TI), 256, 0, stream>>>(
        x, A, c, w1hi, w1lo, g1, bt1, W2, b2, g2, bt2, W3, b3, out);
}

// Round 8
// 236.117 us; speedup vs baseline: 1.9241x; 1.1629x over previous
//
#include <hip/hip_runtime.h>
#include <hip/hip_bf16.h>

#define BB 2048
#define NN 256
#define EE 32
#define HH 64

typedef __attribute__((ext_vector_type(8))) short s16x8;   // 8 bf16 = MFMA A/B frag
typedef __attribute__((ext_vector_type(4))) short s16x4;
typedef __attribute__((ext_vector_type(4))) float f32x4;   // MFMA C/D frag

__device__ __forceinline__ unsigned short f32_to_bf16_rne(float f) {
    unsigned int u = __float_as_uint(f);
    unsigned int r = u + 0x7FFFu + ((u >> 16) & 1u);
    return (unsigned short)(r >> 16);
}
__device__ __forceinline__ float bf16_to_f32(unsigned short h) {
    return __uint_as_float(((unsigned int)h) << 16);
}

// ---------------------------------------------------------------------------
// Split x into hi/lo bf16 (once; L2-resident afterwards). 512 blocks x 256.
// ---------------------------------------------------------------------------
__global__ void prep_x(const float* __restrict__ x,
                       unsigned short* __restrict__ xh,
                       unsigned short* __restrict__ xl) {
    const int i4 = (blockIdx.x * 256 + threadIdx.x) * 4;
    const f32x4 v = *(const f32x4*)(x + i4);
    s16x4 hv, lv;
    #pragma unroll
    for (int q = 0; q < 4; ++q) {
        const unsigned short hb = f32_to_bf16_rne(v[q]);
        hv[q] = (short)hb;
        lv[q] = (short)f32_to_bf16_rne(v[q] - bf16_to_f32(hb));
    }
    *(s16x4*)(xh + i4) = hv;
    *(s16x4*)(xl + i4) = lv;
}

// ---------------------------------------------------------------------------
// Parallelized c precompute: one block (256 thr) per i. Replaces the serial
// 64-thread version (~40-50us tail in rounds 2/7: tiny occupancy + serial
// column gathers).
// ---------------------------------------------------------------------------
__global__ __launch_bounds__(256) void precompute_c(
    const float* __restrict__ A, const float* __restrict__ emb,
    const float* __restrict__ W1, const float* __restrict__ b1,
    float* __restrict__ c) {
    const int i = blockIdx.x;
    const int t = threadIdx.x;
    __shared__ float aS[NN];
    __shared__ float red[256];
    __shared__ float peS[EE];

    const float a_t = A[t * NN + i];
    aS[t] = a_t;
    red[t] = a_t;
    __syncthreads();
    #pragma unroll
    for (int s = 128; s > 0; s >>= 1) {
        if (t < s) red[t] += red[t + s];
        __syncthreads();
    }
    const float inv = 1.f / (red[0] + 1e-8f);   // colsum_i

    // pe[e] = inv * sum_j aS[j]*emb[j,e];  t = jg*32 + e, 8 j-groups of 32
    const int e = t & 31, jg = t >> 5;
    float part = 0.f;
    #pragma unroll 8
    for (int r = 0; r < 32; ++r) {
        const int j = jg * 32 + r;
        part = fmaf(aS[j], emb[j * EE + e], part);
    }
    __syncthreads();          // protect red[0] reads before overwrite
    red[t] = part;
    __syncthreads();
    if (t < 32) {
        float pe = 0.f;
        #pragma unroll
        for (int g = 0; g < 8; ++g) pe += red[g * 32 + t];
        peS[t] = pe * inv;
    }
    __syncthreads();

    if (t < HH) {
        float ch = b1[t];
        const float* embi = emb + i * EE;
        #pragma unroll 8
        for (int e2 = 0; e2 < EE; ++e2) {
            ch = fmaf(embi[e2], W1[(NN      + e2) * HH + t], ch);
            ch = fmaf(peS[e2],  W1[(NN + EE + e2) * HH + t], ch);
        }
        c[i * HH + t] = ch;
    }
}

// ---------------------------------------------------------------------------
// Fused main. Block = (one i, 256 b-rows). 4 waves, wave owns 64 rows.
// Phase 0: fold W1s = diag(A[:,i]) * W1 -> split hi/lo bf16, stored in LDS in
//          lane-linear MFMA B-frag order (frag*1024B + lane*16B) — ds_write/
//          ds_read_b128 both conflict-free.
// Phase 1: h1 = x_split @ W1s_split, 3-term MFMA (xh*wh + xh*wl + xl*wh).
//          A-frags straight from global xh/xl (L2-resident, 2 MB).
// Phase 2: validated epilogue (c-add, LN1, leaky, W2 full-unroll, LN2, W3).
// LDS: Bh|Bl (64 KB) overlaid by h1 (64 KB) after phase-1 barrier; +aS 1 KB.
// ---------------------------------------------------------------------------
__global__ __launch_bounds__(256, 2) void fused_main(
    const unsigned short* __restrict__ xh, const unsigned short* __restrict__ xl,
    const float* __restrict__ A, const float* __restrict__ W1,
    const float* __restrict__ c,
    const float* __restrict__ g1, const float* __restrict__ bt1,
    const float* __restrict__ W2, const float* __restrict__ b2,
    const float* __restrict__ g2, const float* __restrict__ bt2,
    const float* __restrict__ W3, const float* __restrict__ b3,
    float* __restrict__ out) {

    __shared__ float smem[16384];      // 64 KB: Bh(32K)|Bl(32K) then h1
    __shared__ float aS[NN];           // A[:,i]
    unsigned short* Bh = (unsigned short*)smem;
    unsigned short* Bl = Bh + 32 * 512;
    float* h1 = smem;

    const int t  = threadIdx.x;
    const int i  = blockIdx.x & 255;          // consecutive blocks share x in L2
    const int b0 = (blockIdx.x >> 8) * 256;

    const int l  = t & 63;
    const int wv = t >> 6;
    const int lg = l >> 4;     // k-group
    const int lm = l & 15;

    // ---- stage A column ----
    aS[t] = A[t * NN + i];
    __syncthreads();

    // ---- Phase 0: fold W1s into frag-linear split-bf16 LDS ----
    // thread t covers lane l of frags fq*8 .. fq*8+7 (fq = wv)
    #pragma unroll
    for (int fr = 0; fr < 8; ++fr) {
        const int frag = wv * 8 + fr;          // frag = kb*4 + nt
        const int kb = frag >> 2, nt = frag & 3;
        const int h  = nt * 16 + lm;
        const int jb = kb * 32 + lg * 8;
        s16x8 hv, lv;
        #pragma unroll
        for (int w = 0; w < 8; ++w) {
            const int j = jb + w;
            const float p = aS[j] * W1[j * HH + h];
            const unsigned short hb = f32_to_bf16_rne(p);
            hv[w] = (short)hb;
            lv[w] = (short)f32_to_bf16_rne(p - bf16_to_f32(hb));
        }
        *(s16x8*)(Bh + frag * 512 + l * 8) = hv;
        *(s16x8*)(Bl + frag * 512 + l * 8) = lv;
    }
    __syncthreads();

    // ---- Phase 1: MFMA contraction (wave owns rows wv*64 .. wv*64+63) ----
    f32x4 acc[4][4];
    #pragma unroll
    for (int rt = 0; rt < 4; ++rt)
        #pragma unroll
        for (int nt = 0; nt < 4; ++nt) {
            acc[rt][nt][0] = 0.f; acc[rt][nt][1] = 0.f;
            acc[rt][nt][2] = 0.f; acc[rt][nt][3] = 0.f;
        }

    const int rowbase = b0 + wv * 64;
    for (int kb = 0; kb < 8; ++kb) {
        s16x8 bh[4], bl[4];
        #pragma unroll
        for (int nt = 0; nt < 4; ++nt) {
            const int sbase = ((kb * 4 + nt) * 64 + l) * 8;
            bh[nt] = *(const s16x8*)(Bh + sbase);
            bl[nt] = *(const s16x8*)(Bl + sbase);
        }
        const int koff = kb * 32 + lg * 8;
        #pragma unroll
        for (int rt = 0; rt < 4; ++rt) {
            const int row = rowbase + rt * 16 + lm;
            const s16x8 ah = *(const s16x8*)(xh + row * NN + koff);
            const s16x8 al = *(const s16x8*)(xl + row * NN + koff);
            #pragma unroll
            for (int nt = 0; nt < 4; ++nt) {
                acc[rt][nt] = __builtin_amdgcn_mfma_f32_16x16x32_bf16(ah, bh[nt], acc[rt][nt], 0, 0, 0);
                acc[rt][nt] = __builtin_amdgcn_mfma_f32_16x16x32_bf16(ah, bl[nt], acc[rt][nt], 0, 0, 0);
                acc[rt][nt] = __builtin_amdgcn_mfma_f32_16x16x32_bf16(al, bh[nt], acc[rt][nt], 0, 0, 0);
            }
        }
    }
    __syncthreads();   // all B-reads done; safe to overlay h1

    // ---- C-frags -> swizzled h1 (validated layout & swizzle) ----
    #pragma unroll
    for (int rt = 0; rt < 4; ++rt) {
        #pragma unroll
        for (int nt = 0; nt < 4; ++nt) {
            #pragma unroll
            for (int rr = 0; rr < 4; ++rr) {
                const int wr  = wv * 64 + rt * 16 + lg * 4 + rr;
                const int col = nt * 16 + lm;
                const int q   = col >> 2;
                h1[wr * 64 + (((q ^ (wr & 15)) << 2) | (col & 3))] = acc[rt][nt][rr];
            }
        }
    }
    __syncthreads();

    // ---- Phase 2: validated per-row epilogue (thread t owns b-row b0+t) ----
    float acc1[HH];
    #pragma unroll
    for (int q = 0; q < 16; ++q) {
        const f32x4 v = *(const f32x4*)&h1[t * 64 + ((q ^ (t & 15)) << 2)];
        acc1[4*q+0] = v[0]; acc1[4*q+1] = v[1]; acc1[4*q+2] = v[2]; acc1[4*q+3] = v[3];
    }

    // + c (wave-uniform row: i fixed per block)
    {
        const float* crow = c + i * HH;
        #pragma unroll
        for (int h = 0; h < HH; ++h) acc1[h] += crow[h];
    }

    // LayerNorm 1 + leaky relu
    {
        float m0 = 0.f, m1 = 0.f, m2 = 0.f, m3 = 0.f;
        #pragma unroll
        for (int h = 0; h < HH; h += 4) { m0 += acc1[h]; m1 += acc1[h+1]; m2 += acc1[h+2]; m3 += acc1[h+3]; }
        const float m = (m0 + m1 + m2 + m3) * (1.f / HH);
        float v0 = 0.f, v1 = 0.f, v2 = 0.f, v3 = 0.f;
        #pragma unroll
        for (int h = 0; h < HH; h += 4) {
            float d0 = acc1[h] - m, d1 = acc1[h+1] - m, d2 = acc1[h+2] - m, d3 = acc1[h+3] - m;
            v0 = fmaf(d0, d0, v0); v1 = fmaf(d1, d1, v1); v2 = fmaf(d2, d2, v2); v3 = fmaf(d3, d3, v3);
        }
        const float var = (v0 + v1 + v2 + v3) * (1.f / HH);
        const float inv = rsqrtf(var + 1e-5f);
        #pragma unroll
        for (int h = 0; h < HH; ++h) {
            float u = (acc1[h] - m) * inv * g1[h] + bt1[h];
            acc1[h] = (u >= 0.f) ? u : 0.2f * u;
        }
    }

    // Layer 2 (fully unrolled — all indices compile-time constant)
    float acc2[HH];
    #pragma unroll
    for (int ho = 0; ho < HH; ++ho) acc2[ho] = b2[ho];
    #pragma unroll
    for (int h = 0; h < HH; ++h) {
        const float v = acc1[h];
        const float* w = W2 + h * HH;
        #pragma unroll
        for (int ho = 0; ho < HH; ++ho) acc2[ho] = fmaf(v, w[ho], acc2[ho]);
    }

    // LayerNorm 2 + leaky
    {
        float m0 = 0.f, m1 = 0.f, m2 = 0.f, m3 = 0.f;
        #pragma unroll
        for (int h = 0; h < HH; h += 4) { m0 += acc2[h]; m1 += acc2[h+1]; m2 += acc2[h+2]; m3 += acc2[h+3]; }
        const float m = (m0 + m1 + m2 + m3) * (1.f / HH);
        float v0 = 0.f, v1 = 0.f, v2 = 0.f, v3 = 0.f;
        #pragma unroll
        for (int h = 0; h < HH; h += 4) {
            float d0 = acc2[h] - m, d1 = acc2[h+1] - m, d2 = acc2[h+2] - m, d3 = acc2[h+3] - m;
            v0 = fmaf(d0, d0, v0); v1 = fmaf(d1, d1, v1); v2 = fmaf(d2, d2, v2); v3 = fmaf(d3, d3, v3);
        }
        const float var = (v0 + v1 + v2 + v3) * (1.f / HH);
        const float inv = rsqrtf(var + 1e-5f);
        #pragma unroll
        for (int h = 0; h < HH; ++h) {
            float u = (acc2[h] - m) * inv * g2[h] + bt2[h];
            acc2[h] = (u >= 0.f) ? u : 0.2f * u;
        }
    }

    // Layer 3
    float o0 = b3[0], o1 = b3[1];
    #pragma unroll
    for (int h = 0; h < HH; ++h) {
        o0 = fmaf(acc2[h], W3[h * 2 + 0], o0);
        o1 = fmaf(acc2[h], W3[h * 2 + 1], o1);
    }

    const int row = (b0 + t) * NN + i;
    out[row] = o0;
    out[BB * NN + row] = o1;
}

extern "C" void kernel_launch(void* const* d_in, const int* in_sizes, int n_in,
                              void* d_out, int out_size, void* d_ws, size_t ws_size,
                              hipStream_t stream) {
    const float* x   = (const float*)d_in[0];
    const float* A   = (const float*)d_in[1];
    const float* emb = (const float*)d_in[2];
    const float* W1  = (const float*)d_in[3];
    const float* b1  = (const float*)d_in[4];
    const float* g1  = (const float*)d_in[5];
    const float* bt1 = (const float*)d_in[6];
    const float* W2  = (const float*)d_in[7];
    const float* b2  = (const float*)d_in[8];
    const float* g2  = (const float*)d_in[9];
    const float* bt2 = (const float*)d_in[10];
    const float* W3  = (const float*)d_in[11];
    const float* b3  = (const float*)d_in[12];
    float* out = (float*)d_out;

    // ws carve: c (64 KB) | xh (1 MB) | xl (1 MB)
    float* c = (float*)d_ws;
    unsigned short* xhp = (unsigned short*)(c + NN * HH);
    unsigned short* xlp = xhp + BB * NN;

    prep_x<<<(BB * NN) / 1024, 256, 0, stream>>>(x, xhp, xlp);
    precompute_c<<<NN, 256, 0, stream>>>(A, emb, W1, b1, c);
    fused_main<<<NN * (BB / 256), 256, 0, stream>>>(
        xhp, xlp, A, W1, c, g1, bt1, W2, b2, g2, bt2, W3, b3, out);
}